// Round 15
// baseline (423.301 us; speedup 1.0000x reference)
//
#include <hip/hip_runtime.h>

#define NEGV -10000000000.0f

typedef _Float16 half8 __attribute__((ext_vector_type(8)));
typedef float f32x4 __attribute__((ext_vector_type(4)));

__device__ __forceinline__ void gld16(const void* g, void* l) {
  __builtin_amdgcn_global_load_lds((const __attribute__((address_space(1))) void*)g,
                                   (__attribute__((address_space(3))) void*)l,
                                   16, 0, 0);
}

__device__ __forceinline__ float fast_tanh(float x) {
  const float e = __expf(2.0f * x);
  return 1.0f - 2.0f * __builtin_amdgcn_rcpf(e + 1.0f);
}

// ---------------------------------------------------------------------------
// PREP (one launch): blocks [0,128) hproj | [128,1152) wconv. No encconv.
// ---------------------------------------------------------------------------
__global__ __launch_bounds__(256) void prep_kernel(
    const float* __restrict__ We, _Float16* __restrict__ W16T,
    const float* __restrict__ hidden, const float* __restrict__ W_h,
    const float* __restrict__ b_h, const float* __restrict__ b_e,
    float* __restrict__ hpb) {
  __shared__ float tile[32][33];
  const int bid = blockIdx.x;
  const int tid = threadIdx.x;

  if (bid < 128) {
    // ---- hproj ----
    const int b = bid >> 2;
    const int h = ((bid & 3) << 8) | tid;
    const float* hb = hidden + b * 1024;
    float a0 = 0.f, a1 = 0.f, a2 = 0.f, a3 = 0.f;
    #pragma unroll 4
    for (int k = 0; k < 1024; k += 4) {
      a0 = fmaf(hb[k + 0], W_h[(size_t)(k + 0) * 1024 + h], a0);
      a1 = fmaf(hb[k + 1], W_h[(size_t)(k + 1) * 1024 + h], a1);
      a2 = fmaf(hb[k + 2], W_h[(size_t)(k + 2) * 1024 + h], a2);
      a3 = fmaf(hb[k + 3], W_h[(size_t)(k + 3) * 1024 + h], a3);
    }
    hpb[b * 1024 + h] = b_h[h] + b_e[h] + ((a0 + a1) + (a2 + a3));
  } else {
    // ---- wconv: W16T[n][k] = (fp16) W_e[k][n] ----
    const int tb = bid - 128;
    const int n0 = (tb & 31) << 5, k0 = (tb >> 5) << 5;
    const int tx = tid & 31, ty = tid >> 5;  // 32 x 8
    #pragma unroll
    for (int i = 0; i < 4; ++i) {
      const int r = ty + (i << 3);
      tile[r][tx] = We[(size_t)(k0 + r) * 1024 + n0 + tx];
    }
    __syncthreads();
    #pragma unroll
    for (int i = 0; i < 4; ++i) {
      const int r = ty + (i << 3);
      W16T[(size_t)(n0 + r) * 1024 + k0 + tx] = (_Float16)tile[tx][r];
    }
  }
}

// ---------------------------------------------------------------------------
// FUSED GEMM, BK=64 double-buffer, ONE barrier per K-tile (64 total, was 128):
//   logits[b,s] = mask ? v . tanh(hpb[b,:] + enc[b,s,:]@W_e) : NEG
// BM=256, BN=256 (4 panels), BK=64, 512 threads, 8 waves 2Mx4N, per-wave
// 128x64 (acc[8][4]), 64 MFMA/wave/tile in two kk-halves.
//  - A: fp32 loads -> af regs (issued mid-tile t for t+2) -> cvt -> swizzled
//    ds_write into Abuf[npar] (A data for t+1; af has a full-tile leash).
//  - B: gld_lds from W16T (L2-resident) into Bbuf[npar], pre-swizzled source.
//  - 2-buffer safety: npar's stage-writes only start after the barrier that
//    ended npar's reads (t-1 end). Reads of par never overlap writes.
//  - Ledger (FIFO, in-order vmcnt): entering tile t, outstanding=[A(t+1)x8].
//    Compiler's af-wait at writeA drains A(t+1) (issued 1 tile ago; instant).
//    Then stageB(t+1)x4, issueA(t+2)x8 -> tile-end vmcnt(8) retires B(t+1),
//    leaves A(t+2) in flight. Never a cold drain in steady state.
//  - Swizzle (128B rows = 8 granules): slot = g ^ (row&7) on BOTH stage side
//    and read side (canonical G4 XOR for 128B rows; rows 0-7 cover all 32
//    banks, rows 8-15 free 2-way).
// LDS: 2x32K A + 2x32K B + 4K hp + 4K v + 4K red = 140 KB (1 block/CU).
// ---------------------------------------------------------------------------
__global__ __launch_bounds__(512, 2) void attn_gemm8_kernel(
    const float* __restrict__ enc32, const _Float16* __restrict__ W16T,
    const float* __restrict__ hpb, const float* __restrict__ v,
    const int* __restrict__ mask, float* __restrict__ logits) {
  __shared__ __align__(16) _Float16 Abuf[2][256 * 64];  // 64 KB
  __shared__ __align__(16) _Float16 Bbuf[2][256 * 64];  // 64 KB
  __shared__ float hp_s[1024];
  __shared__ float vh_s[1024];
  __shared__ float red[1024];

  const int tid = threadIdx.x;
  const int wid = tid >> 6;
  const int lane = tid & 63;
  const int l15 = lane & 15;
  const int qq = lane >> 4;        // 16B granule within a 64B kk-half
  const int wr = wid >> 2;         // 0..1: rows [wr*128, +128)
  const int wc = wid & 3;          // 0..3: cols [wc*64, +64) within the panel
  const int m0 = blockIdx.x << 8;  // 256 rows per block
  const int b = blockIdx.x >> 3;   // 8 blocks per batch

  for (int i = tid; i < 1024; i += 512) {
    hp_s[i] = hpb[(b << 10) + i];
    vh_s[i] = v[i];
  }

  // ---- staging constants: granule gid = tid + 512i -> row=gid>>3, g=tid&7 ----
  const int rA = tid >> 3;                       // base row (0..63), +64i
  const int g0 = tid & 7;                        // granule within 128B row
  const int swz = (g0 ^ (rA & 7)) << 4;          // swizzled slot byte (row&7 == rA&7 for +64i)
  const int ldsB = (wid << 10);                  // wave-uniform B dest base

  const float* encb = enc32 + (size_t)m0 * 1024;
  const char* wb0 = (const char*)W16T;

  // A: 8 fp32x4 loads (2 per granule x 4 rows), true cols g0*8..g0*8+7
  f32x4 af[8];
  auto issueA = [&](int t) {
    #pragma unroll
    for (int i = 0; i < 4; ++i) {
      const int row = rA + (i << 6);
      const float* p = encb + (size_t)row * 1024 + ((t & 15) << 6) + (g0 << 3);
      af[2 * i] = *(const f32x4*)p;
      af[2 * i + 1] = *(const f32x4*)(p + 4);
    }
  };
  auto writeA = [&](int buf) {
    char* Ab = (char*)(&Abuf[buf][0]);
    #pragma unroll
    for (int i = 0; i < 4; ++i) {
      const int row = rA + (i << 6);
      half8 h;
      #pragma unroll
      for (int j = 0; j < 4; ++j) {
        h[j] = (_Float16)af[2 * i][j];
        h[4 + j] = (_Float16)af[2 * i + 1][j];
      }
      *(half8*)(Ab + (row << 7) + swz) = h;  // slot g0^(row&7) holds true col g0
    }
  };
  // B: 4 gld_lds, linear dest, pre-swizzled source col
  auto stageB = [&](int buf, int t) {
    const char* wb = wb0 + ((size_t)(t >> 4) << 19);  // panel * 256*2048 B
    char* base = (char*)(&Bbuf[buf][0]) + ldsB;
    #pragma unroll
    for (int i = 0; i < 4; ++i) {
      const int row = rA + (i << 6);
      const int col = ((t & 15) << 7) + swz;  // source col = slot's true col
      gld16(wb + (size_t)row * 2048 + col, base + (i << 13));
    }
  };

  // ---- read-side offsets (loop-invariant, swizzled) ----
  int aoff[2][2][4], boff[2][4];  // [kk][mh][mi] / [kk][ni]
  #pragma unroll
  for (int kk = 0; kk < 2; ++kk) {
    #pragma unroll
    for (int mh = 0; mh < 2; ++mh)
      #pragma unroll
      for (int mi = 0; mi < 4; ++mi) {
        const int row = (wr << 7) + (mh << 6) + (mi << 4) + l15;
        aoff[kk][mh][mi] = (row << 7) + ((((kk << 2) + qq) ^ (row & 7)) << 4);
      }
    #pragma unroll
    for (int ni = 0; ni < 4; ++ni) {
      const int np = (wc << 6) + (ni << 4) + l15;
      boff[kk][ni] = (np << 7) + ((((kk << 2) + qq) ^ (np & 7)) << 4);
    }
  }

  f32x4 acc[8][4];
  float rowsum[8][4];
  #pragma unroll
  for (int mi = 0; mi < 8; ++mi)
    #pragma unroll
    for (int j = 0; j < 4; ++j) {
      acc[mi][j] = (f32x4){0.f, 0.f, 0.f, 0.f};
      rowsum[mi][j] = 0.f;
    }

  // ---- prologue: A(0)->buf0 via regs; B(0) staged; af <- A(1) ----
  issueA(0);
  asm volatile("s_waitcnt vmcnt(0)" ::: "memory");
  writeA(0);
  stageB(0, 0);
  issueA(1);
  __syncthreads();  // one-time full drain: B(0) landed, A(0) published

  #pragma unroll 1
  for (int t = 0; t < 64; ++t) {
    const int par = t & 1, npar = par ^ 1;
    const char* A = (const char*)(&Abuf[par][0]);
    const char* B = (const char*)(&Bbuf[par][0]);
    half8 a[2][4], bf[4];

    // ======== kk = 0: 12 ds_read + 32 MFMA ========
    #pragma unroll
    for (int mi = 0; mi < 4; ++mi) a[0][mi] = *(const half8*)(A + aoff[0][0][mi]);
    #pragma unroll
    for (int ni = 0; ni < 4; ++ni) bf[ni] = *(const half8*)(B + boff[0][ni]);
    #pragma unroll
    for (int mi = 0; mi < 4; ++mi) a[1][mi] = *(const half8*)(A + aoff[0][1][mi]);
    __builtin_amdgcn_s_setprio(1);
    #pragma unroll
    for (int mh = 0; mh < 2; ++mh)
      #pragma unroll
      for (int mi = 0; mi < 4; ++mi)
        #pragma unroll
        for (int ni = 0; ni < 4; ++ni)
          acc[(mh << 2) + mi][ni] =
              __builtin_amdgcn_mfma_f32_16x16x32_f16(a[mh][mi], bf[ni], acc[(mh << 2) + mi][ni], 0, 0, 0);
    __builtin_amdgcn_s_setprio(0);

    // ======== mid-tile staging (all target npar; never the read buffer) ====
    if (t < 63) {
      writeA(npar);        // compiler waits af = A(t+1), issued 1 tile ago
      stageB(npar, t + 1); // FIFO +4
    }
    if (t < 62) issueA(t + 2);  // FIFO +8 (af reload after consume; in-order safe)

    // ======== kk = 1: 12 ds_read + 32 MFMA ========
    #pragma unroll
    for (int mi = 0; mi < 4; ++mi) a[0][mi] = *(const half8*)(A + aoff[1][0][mi]);
    #pragma unroll
    for (int ni = 0; ni < 4; ++ni) bf[ni] = *(const half8*)(B + boff[1][ni]);
    #pragma unroll
    for (int mi = 0; mi < 4; ++mi) a[1][mi] = *(const half8*)(A + aoff[1][1][mi]);
    __builtin_amdgcn_s_setprio(1);
    #pragma unroll
    for (int mh = 0; mh < 2; ++mh)
      #pragma unroll
      for (int mi = 0; mi < 4; ++mi)
        #pragma unroll
        for (int ni = 0; ni < 4; ++ni)
          acc[(mh << 2) + mi][ni] =
              __builtin_amdgcn_mfma_f32_16x16x32_f16(a[mh][mi], bf[ni], acc[(mh << 2) + mi][ni], 0, 0, 0);
    __builtin_amdgcn_s_setprio(0);

    // ======== tile end: counted vmcnt + publish + ONE barrier ========
    if (t < 62) asm volatile("s_waitcnt vmcnt(8)" ::: "memory");   // B(t+1) landed; A(t+2) flies
    else        asm volatile("s_waitcnt vmcnt(0)" ::: "memory");
    asm volatile("s_waitcnt lgkmcnt(0)" ::: "memory");             // ds_writes published
    __builtin_amdgcn_s_barrier();

    // ---- per-panel epilogue: rowsum += tanh(acc + hproj) * v ----
    if ((t & 15) == 15) {
      const int nt = t >> 4;
      const int hb = (nt << 8) + (wc << 6);
      #pragma unroll
      for (int ni = 0; ni < 4; ++ni) {
        const int h = hb + (ni << 4) + l15;
        const float hv = hp_s[h];
        const float vv = vh_s[h];
        #pragma unroll
        for (int mi = 0; mi < 8; ++mi) {
          #pragma unroll
          for (int r = 0; r < 4; ++r)
            rowsum[mi][r] += fast_tanh(acc[mi][ni][r] + hv) * vv;
          acc[mi][ni] = (f32x4){0.f, 0.f, 0.f, 0.f};
        }
      }
    }
  }

  // ---- reduce across the 16 column-lanes of each wave ----
  #pragma unroll
  for (int mi = 0; mi < 8; ++mi)
    #pragma unroll
    for (int r = 0; r < 4; ++r) {
      float s = rowsum[mi][r];
      s += __shfl_xor(s, 1);
      s += __shfl_xor(s, 2);
      s += __shfl_xor(s, 4);
      s += __shfl_xor(s, 8);
      rowsum[mi][r] = s;
    }
  __syncthreads();
  if (l15 == 0) {
    #pragma unroll
    for (int mi = 0; mi < 8; ++mi)
      #pragma unroll
      for (int r = 0; r < 4; ++r) {
        const int row = (wr << 7) + (mi << 4) + (qq << 2) + r;
        red[(row << 2) + wc] = rowsum[mi][r];
      }
  }
  __syncthreads();
  if (tid < 256) {
    const float s = red[tid << 2] + red[(tid << 2) + 1] + red[(tid << 2) + 2] + red[(tid << 2) + 3];
    const int m = m0 + tid;
    logits[m] = (mask[(b << 11) + (m & 2047)] == 0) ? NEGV : s;
  }
}

// ---------------------------------------------------------------------------
// softmax over S=2048 per batch row -> attention weights (output 1)
// ---------------------------------------------------------------------------
__global__ void softmax_kernel(const float* __restrict__ logits, float* __restrict__ wout) {
  __shared__ float red[4];
  const int b = blockIdx.x, tid = threadIdx.x;
  const int wid = tid >> 6, lane = tid & 63;
  const float* lb = logits + b * 2048;
  float x[8];
  #pragma unroll
  for (int j = 0; j < 8; ++j) x[j] = lb[tid + j * 256];
  float m = x[0];
  #pragma unroll
  for (int j = 1; j < 8; ++j) m = fmaxf(m, x[j]);
  #pragma unroll
  for (int off = 32; off > 0; off >>= 1) m = fmaxf(m, __shfl_xor(m, off));
  if (lane == 0) red[wid] = m;
  __syncthreads();
  m = fmaxf(fmaxf(red[0], red[1]), fmaxf(red[2], red[3]));
  __syncthreads();
  float e[8];
  float s = 0.f;
  #pragma unroll
  for (int j = 0; j < 8; ++j) { e[j] = expf(x[j] - m); s += e[j]; }
  #pragma unroll
  for (int off = 32; off > 0; off >>= 1) s += __shfl_xor(s, off);
  if (lane == 0) red[wid] = s;
  __syncthreads();
  s = red[0] + red[1] + red[2] + red[3];
  const float inv = 1.0f / s;
  #pragma unroll
  for (int j = 0; j < 8; ++j) wout[b * 2048 + tid + j * 256] = e[j] * inv;
}

// ---------------------------------------------------------------------------
// context from fp32 enc: ctx[b,e] = sum_s w[b,s] * enc[b,s,e]
// ---------------------------------------------------------------------------
__global__ void context_kernel(const float* __restrict__ enc, const float* __restrict__ wout,
                               float* __restrict__ ctx) {
  const int b = blockIdx.x >> 4;
  const int ch = blockIdx.x & 15;
  const int tid = threadIdx.x;
  float ax = 0.f, ay = 0.f, az = 0.f, aw = 0.f;
  const int s0 = ch * 128;
  for (int i = 0; i < 128; ++i) {
    const int s = s0 + i;
    const float w = wout[b * 2048 + s];
    const float4 r = *(const float4*)(enc + (size_t)(b * 2048 + s) * 1024 + tid * 4);
    ax = fmaf(w, r.x, ax);
    ay = fmaf(w, r.y, ay);
    az = fmaf(w, r.z, az);
    aw = fmaf(w, r.w, aw);
  }
  float* c = ctx + b * 1024 + tid * 4;
  atomicAdd(c + 0, ax);
  atomicAdd(c + 1, ay);
  atomicAdd(c + 2, az);
  atomicAdd(c + 3, aw);
}

// ---------------------------------------------------------------------------
extern "C" void kernel_launch(void* const* d_in, const int* in_sizes, int n_in,
                              void* d_out, int out_size, void* d_ws, size_t ws_size,
                              hipStream_t stream) {
  const float* hidden = (const float*)d_in[0];
  const float* enc    = (const float*)d_in[1];
  const int*   mask   = (const int*)d_in[2];
  const float* W_h    = (const float*)d_in[3];
  const float* b_h    = (const float*)d_in[4];
  const float* W_e    = (const float*)d_in[5];
  const float* b_e    = (const float*)d_in[6];
  const float* v      = (const float*)d_in[7];

  float* ctx  = (float*)d_out;              // context: 32*1024 floats
  float* wout = (float*)d_out + 32 * 1024;  // attention weights: 32*2048 floats

  char* ws = (char*)d_ws;
  _Float16* W16T = (_Float16*)ws;                                   // 2 MB
  float* hpb     = (float*)(ws + 2097152);                          // 128 KB
  float* logits  = (float*)(ws + 2097152 + 131072);                 // 256 KB

  hipMemsetAsync(ctx, 0, 32 * 1024 * sizeof(float), stream);
  hipLaunchKernelGGL(prep_kernel, dim3(1152), dim3(256), 0, stream,
                     W_e, W16T, hidden, W_h, b_h, b_e, hpb);
  hipLaunchKernelGGL(attn_gemm8_kernel, dim3(256), dim3(512), 0, stream,
                     enc, W16T, hpb, v, mask, logits);
  hipLaunchKernelGGL(softmax_kernel, dim3(32), dim3(256), 0, stream, logits, wout);
  hipLaunchKernelGGL(context_kernel, dim3(512), dim3(256), 0, stream, enc, wout, ctx);
}

// Round 16
// 386.425 us; speedup vs baseline: 1.0954x; 1.0954x over previous
//
#include <hip/hip_runtime.h>

#define NEGV -10000000000.0f

typedef _Float16 half8 __attribute__((ext_vector_type(8)));
typedef float f32x4 __attribute__((ext_vector_type(4)));

__device__ __forceinline__ void gld16(const void* g, void* l) {
  __builtin_amdgcn_global_load_lds((const __attribute__((address_space(1))) void*)g,
                                   (__attribute__((address_space(3))) void*)l,
                                   16, 0, 0);
}

__device__ __forceinline__ float fast_tanh(float x) {
  const float e = __expf(2.0f * x);
  return 1.0f - 2.0f * __builtin_amdgcn_rcpf(e + 1.0f);
}

// ---------------------------------------------------------------------------
// PREP (one launch): blocks [0,128) hproj | [128,1152) wconv. No encconv:
// the GEMM persists its panel-0 fp16 A-tiles to enc16 as a byproduct.
// ---------------------------------------------------------------------------
__global__ __launch_bounds__(256) void prep_kernel(
    const float* __restrict__ We, _Float16* __restrict__ W16T,
    const float* __restrict__ hidden, const float* __restrict__ W_h,
    const float* __restrict__ b_h, const float* __restrict__ b_e,
    float* __restrict__ hpb) {
  __shared__ float tile[32][33];
  const int bid = blockIdx.x;
  const int tid = threadIdx.x;

  if (bid < 128) {
    // ---- hproj ----
    const int b = bid >> 2;
    const int h = ((bid & 3) << 8) | tid;
    const float* hb = hidden + b * 1024;
    float a0 = 0.f, a1 = 0.f, a2 = 0.f, a3 = 0.f;
    #pragma unroll 4
    for (int k = 0; k < 1024; k += 4) {
      a0 = fmaf(hb[k + 0], W_h[(size_t)(k + 0) * 1024 + h], a0);
      a1 = fmaf(hb[k + 1], W_h[(size_t)(k + 1) * 1024 + h], a1);
      a2 = fmaf(hb[k + 2], W_h[(size_t)(k + 2) * 1024 + h], a2);
      a3 = fmaf(hb[k + 3], W_h[(size_t)(k + 3) * 1024 + h], a3);
    }
    hpb[b * 1024 + h] = b_h[h] + b_e[h] + ((a0 + a1) + (a2 + a3));
  } else {
    // ---- wconv: W16T[n][k] = (fp16) W_e[k][n] ----
    const int tb = bid - 128;
    const int n0 = (tb & 31) << 5, k0 = (tb >> 5) << 5;
    const int tx = tid & 31, ty = tid >> 5;  // 32 x 8
    #pragma unroll
    for (int i = 0; i < 4; ++i) {
      const int r = ty + (i << 3);
      tile[r][tx] = We[(size_t)(k0 + r) * 1024 + n0 + tx];
    }
    __syncthreads();
    #pragma unroll
    for (int i = 0; i < 4; ++i) {
      const int r = ty + (i << 3);
      W16T[(size_t)(n0 + r) * 1024 + k0 + tx] = (_Float16)tile[tx][r];
    }
  }
}

// ---------------------------------------------------------------------------
// FUSED GEMM = R12's measured-best (257us total) kernel, UNCHANGED read path,
// + panel-0 enc16 persistence:
//   logits[b,s] = mask ? v . tanh(hpb[b,:] + enc[b,s,:]@W_e) : NEG
// BM=256, BN=256 (4 panels), BK=32, 512 threads, 8 waves 2Mx4N, per-wave
// 128x64 (acc[8][4]).
//  - A: fp32 loads -> af regs -> cvt -> swizzled ds_write (3-buffer).
//    During panel 0 (t<32) the converted h0/h1 are ALSO stored to enc16
//    (t=0..30 cover k-tiles 1..31; t=31 writes A(32)=k-tile 0 -> complete).
//    Context then reads fp16 (21us vs 41us fp32).
//  - B: gld_lds from W16T (L2-resident), stage t+2.
//  - Ledger (FIFO, in-order retirement): panel-0 tile end outstanding =
//    [B(t+1)x2, st x2, A(t+2)x4, B(t+2)x2] -> vmcnt(8) retires B(t+1);
//    stores drain in background; at t=32 the compiler's af-wait absorbs the
//    last stores; t>=32 tile end = [B(t+1)x2, A(t+2)x4, B(t+2)x2] -> vmcnt(6).
//    Never a cold drain in the main loop.
// Swizzle: g ^= (row>>1)&3 both sides (0-conflict, R4-R12).
// ---------------------------------------------------------------------------
__global__ __launch_bounds__(512, 2) void attn_gemm8_kernel(
    const float* __restrict__ enc32, _Float16* __restrict__ enc16,
    const _Float16* __restrict__ W16T,
    const float* __restrict__ hpb, const float* __restrict__ v,
    const int* __restrict__ mask, float* __restrict__ logits) {
  __shared__ __align__(16) _Float16 Abuf[3][256 * 32];  // 48 KB
  __shared__ __align__(16) _Float16 Bbuf[3][256 * 32];  // 48 KB
  __shared__ float hp_s[1024];
  __shared__ float vh_s[1024];
  __shared__ float red[1024];

  const int tid = threadIdx.x;
  const int wid = tid >> 6;
  const int lane = tid & 63;
  const int l15 = lane & 15;
  const int qq = lane >> 4;        // 16B granule within the 64B row
  const int wr = wid >> 2;         // 0..1: rows [wr*128, +128)
  const int wc = wid & 3;          // 0..3: cols [wc*64, +64) within the panel
  const int m0 = blockIdx.x << 8;  // 256 rows per block
  const int b = blockIdx.x >> 3;   // 8 blocks per batch

  for (int i = tid; i < 1024; i += 512) {
    hp_s[i] = hpb[(b << 10) + i];
    vh_s[i] = v[i];
  }

  // ---- staging constants ----
  const int r0 = tid >> 2;                     // A/B row, issue 0 (0..127)
  const int r1 = r0 + 128;                     // issue 1 (same swz bits)
  const int g0 = tid & 3;                      // 16B granule within 64B row
  const int swzd = (g0 ^ ((r0 >> 1) & 3)) << 4;  // dest-swizzled LDS col byte
  const int scB = swzd;                          // B source col (inverse swz)
  const int ldsoff0 = (wid << 10);
  const int ldsoff1 = (wid << 10) + 8192;

  const float* encb = enc32 + (size_t)m0 * 1024;
  _Float16* enc16b = enc16 + (size_t)m0 * 1024;
  const char* wb0 = (const char*)W16T;

  // A: plain fp32 loads into regs (true col = g0*8 within the 32-wide k-tile)
  f32x4 af[4];
  auto issueA = [&](int t) {
    const float* p0 = encb + (size_t)r0 * 1024 + ((t & 31) << 5) + (g0 << 3);
    const float* p1 = encb + (size_t)r1 * 1024 + ((t & 31) << 5) + (g0 << 3);
    af[0] = *(const f32x4*)p0; af[1] = *(const f32x4*)(p0 + 4);
    af[2] = *(const f32x4*)p1; af[3] = *(const f32x4*)(p1 + 4);
  };
  // writeA for tile t1: LDS write always; persist to enc16 iff 1 <= t1 <= 32
  auto writeA = [&](int buf, int t1) {
    half8 h0, h1;
    #pragma unroll
    for (int j = 0; j < 4; ++j) {
      h0[j] = (_Float16)af[0][j]; h0[4 + j] = (_Float16)af[1][j];
      h1[j] = (_Float16)af[2][j]; h1[4 + j] = (_Float16)af[3][j];
    }
    char* Ab = (char*)(&Abuf[buf][0]);
    *(half8*)(Ab + (r0 << 6) + swzd) = h0;
    *(half8*)(Ab + (r1 << 6) + swzd) = h1;
    if (t1 >= 1 && t1 <= 32) {
      const int kc = ((t1 & 31) << 5) + (g0 << 3);
      *(half8*)(enc16b + (size_t)r0 * 1024 + kc) = h0;
      *(half8*)(enc16b + (size_t)r1 * 1024 + kc) = h1;
    }
  };
  // B: gld_lds from W16T (unchanged from R12)
  auto stageB = [&](int buf, int t) {
    const char* wb = wb0 + ((size_t)(t >> 5) << 19);  // panel * 256*2048 B
    const int colb = ((t & 31) << 6) + scB;
    char* base = (char*)(&Bbuf[buf][0]);
    gld16(wb + (size_t)r0 * 2048 + colb, base + ldsoff0);
    gld16(wb + (size_t)r1 * 2048 + colb, base + ldsoff1);
  };

  // ---- read-side offsets (loop-invariant, swizzled; unchanged) ----
  int aoff[2][4], boff[4];
  #pragma unroll
  for (int mh = 0; mh < 2; ++mh)
    #pragma unroll
    for (int mi = 0; mi < 4; ++mi) {
      const int row = (wr << 7) + (mh << 6) + (mi << 4) + l15;
      aoff[mh][mi] = (row << 6) + ((qq ^ ((row >> 1) & 3)) << 4);
    }
  #pragma unroll
  for (int ni = 0; ni < 4; ++ni) {
    const int np = (wc << 6) + (ni << 4) + l15;
    boff[ni] = (np << 6) + ((qq ^ ((np >> 1) & 3)) << 4);
  }

  f32x4 acc[8][4];
  float rowsum[8][4];
  #pragma unroll
  for (int mi = 0; mi < 8; ++mi)
    #pragma unroll
    for (int j = 0; j < 4; ++j) {
      acc[mi][j] = (f32x4){0.f, 0.f, 0.f, 0.f};
      rowsum[mi][j] = 0.f;
    }

  // ---- prologue: A(0)->buf0 via regs; B(0),B(1) staged; af <- A(1) ----
  issueA(0);
  stageB(0, 0); stageB(1, 1);
  asm volatile("s_waitcnt vmcnt(4)" ::: "memory");  // A(0) regs ready
  writeA(0, 0);                                     // no persist (t1=0)
  issueA(1);
  __syncthreads();  // full drain: B(0),B(1) landed, A(0) published

  #pragma unroll 1
  for (int t = 0; t < 128; ++t) {
    const int bi = t % 3;
    const int bi1 = (bi >= 2) ? 0 : bi + 1;       // (t+1)%3
    const int bi2 = (bi1 >= 2) ? 0 : bi1 + 1;     // (t+2)%3
    const char* A = (const char*)(&Abuf[bi][0]);
    const char* B = (const char*)(&Bbuf[bi][0]);
    half8 a0[4], a1[4], bf[4];

    // ---- issue all 12 ds_reads up front (compiler places counted waits) ----
    #pragma unroll
    for (int mi = 0; mi < 4; ++mi) a0[mi] = *(const half8*)(A + aoff[0][mi]);
    #pragma unroll
    for (int ni = 0; ni < 4; ++ni) bf[ni] = *(const half8*)(B + boff[ni]);
    #pragma unroll
    for (int mi = 0; mi < 4; ++mi) a1[mi] = *(const half8*)(A + aoff[1][mi]);

    // ---- cvt + write A(t+1); persist to enc16 during panel 0 ----
    if (t < 127) writeA(bi1, t + 1);
    // ---- issue next loads: A(t+2) regs, B(t+2) gld_lds ----
    if (t < 126) { issueA(t + 2); stageB(bi2, t + 2); }

    // ---- MFMA clusters; reads drain underneath via per-operand waits ----
    __builtin_amdgcn_s_setprio(1);
    #pragma unroll
    for (int mi = 0; mi < 4; ++mi)
      #pragma unroll
      for (int ni = 0; ni < 4; ++ni)
        acc[mi][ni] = __builtin_amdgcn_mfma_f32_16x16x32_f16(a0[mi], bf[ni], acc[mi][ni], 0, 0, 0);
    #pragma unroll
    for (int mi = 0; mi < 4; ++mi)
      #pragma unroll
      for (int ni = 0; ni < 4; ++ni)
        acc[4 + mi][ni] = __builtin_amdgcn_mfma_f32_16x16x32_f16(a1[mi], bf[ni], acc[4 + mi][ni], 0, 0, 0);
    __builtin_amdgcn_s_setprio(0);

    // ---- tile-end sync: counted vmcnt; publish ds_writes; barrier ----
    if (t < 32)       asm volatile("s_waitcnt vmcnt(8)" ::: "memory");  // +2 stores in flight
    else if (t < 126) asm volatile("s_waitcnt vmcnt(6)" ::: "memory");
    else              asm volatile("s_waitcnt vmcnt(0)" ::: "memory");
    asm volatile("s_waitcnt lgkmcnt(0)" ::: "memory");
    __builtin_amdgcn_s_barrier();

    // ---- per-panel epilogue: rowsum += tanh(acc + hproj) * v ----
    if ((t & 31) == 31) {
      const int nt = t >> 5;
      const int hb = (nt << 8) + (wc << 6);
      #pragma unroll
      for (int ni = 0; ni < 4; ++ni) {
        const int h = hb + (ni << 4) + l15;
        const float hv = hp_s[h];
        const float vv = vh_s[h];
        #pragma unroll
        for (int mi = 0; mi < 8; ++mi) {
          #pragma unroll
          for (int r = 0; r < 4; ++r)
            rowsum[mi][r] += fast_tanh(acc[mi][ni][r] + hv) * vv;
          acc[mi][ni] = (f32x4){0.f, 0.f, 0.f, 0.f};
        }
      }
    }
  }

  // ---- reduce across the 16 column-lanes of each wave ----
  #pragma unroll
  for (int mi = 0; mi < 8; ++mi)
    #pragma unroll
    for (int r = 0; r < 4; ++r) {
      float s = rowsum[mi][r];
      s += __shfl_xor(s, 1);
      s += __shfl_xor(s, 2);
      s += __shfl_xor(s, 4);
      s += __shfl_xor(s, 8);
      rowsum[mi][r] = s;
    }
  __syncthreads();
  if (l15 == 0) {
    #pragma unroll
    for (int mi = 0; mi < 8; ++mi)
      #pragma unroll
      for (int r = 0; r < 4; ++r) {
        const int row = (wr << 7) + (mi << 4) + (qq << 2) + r;
        red[(row << 2) + wc] = rowsum[mi][r];
      }
  }
  __syncthreads();
  if (tid < 256) {
    const float s = red[tid << 2] + red[(tid << 2) + 1] + red[(tid << 2) + 2] + red[(tid << 2) + 3];
    const int m = m0 + tid;
    logits[m] = (mask[(b << 11) + (m & 2047)] == 0) ? NEGV : s;
  }
}

// ---------------------------------------------------------------------------
// softmax over S=2048 per batch row -> attention weights (output 1)
// ---------------------------------------------------------------------------
__global__ void softmax_kernel(const float* __restrict__ logits, float* __restrict__ wout) {
  __shared__ float red[4];
  const int b = blockIdx.x, tid = threadIdx.x;
  const int wid = tid >> 6, lane = tid & 63;
  const float* lb = logits + b * 2048;
  float x[8];
  #pragma unroll
  for (int j = 0; j < 8; ++j) x[j] = lb[tid + j * 256];
  float m = x[0];
  #pragma unroll
  for (int j = 1; j < 8; ++j) m = fmaxf(m, x[j]);
  #pragma unroll
  for (int off = 32; off > 0; off >>= 1) m = fmaxf(m, __shfl_xor(m, off));
  if (lane == 0) red[wid] = m;
  __syncthreads();
  m = fmaxf(fmaxf(red[0], red[1]), fmaxf(red[2], red[3]));
  __syncthreads();
  float e[8];
  float s = 0.f;
  #pragma unroll
  for (int j = 0; j < 8; ++j) { e[j] = expf(x[j] - m); s += e[j]; }
  #pragma unroll
  for (int off = 32; off > 0; off >>= 1) s += __shfl_xor(s, off);
  if (lane == 0) red[wid] = s;
  __syncthreads();
  s = red[0] + red[1] + red[2] + red[3];
  const float inv = 1.0f / s;
  #pragma unroll
  for (int j = 0; j < 8; ++j) wout[b * 2048 + tid + j * 256] = e[j] * inv;
}

// ---------------------------------------------------------------------------
// context from fp16 enc (written by the GEMM's panel-0 persistence):
//   ctx[b,e] = sum_s w[b,s] * enc16[b,s,e]
// ---------------------------------------------------------------------------
__global__ void context16_kernel(const _Float16* __restrict__ enc16,
                                 const float* __restrict__ wout, float* __restrict__ ctx) {
  const int b = blockIdx.x >> 4;
  const int ch = blockIdx.x & 15;
  const int tl = threadIdx.x & 127;  // e-granule: 8 cols
  const int sh = threadIdx.x >> 7;   // 0/1: s interleave
  float a[8] = {0.f, 0.f, 0.f, 0.f, 0.f, 0.f, 0.f, 0.f};
  #pragma unroll 1
  for (int i = 0; i < 64; ++i) {
    const int s = (ch << 7) + (i << 1) + sh;
    const float w = wout[(b << 11) + s];
    const half8 r = *(const half8*)(enc16 + (((size_t)(b << 11) + s) << 10) + (tl << 3));
    #pragma unroll
    for (int j = 0; j < 8; ++j) a[j] = fmaf(w, (float)r[j], a[j]);
  }
  float* c = ctx + (b << 10) + (tl << 3);
  #pragma unroll
  for (int j = 0; j < 8; ++j) atomicAdd(c + j, a[j]);
}

// ---------------------------------------------------------------------------
extern "C" void kernel_launch(void* const* d_in, const int* in_sizes, int n_in,
                              void* d_out, int out_size, void* d_ws, size_t ws_size,
                              hipStream_t stream) {
  const float* hidden = (const float*)d_in[0];
  const float* enc    = (const float*)d_in[1];
  const int*   mask   = (const int*)d_in[2];
  const float* W_h    = (const float*)d_in[3];
  const float* b_h    = (const float*)d_in[4];
  const float* W_e    = (const float*)d_in[5];
  const float* b_e    = (const float*)d_in[6];
  const float* v      = (const float*)d_in[7];

  float* ctx  = (float*)d_out;              // context: 32*1024 floats
  float* wout = (float*)d_out + 32 * 1024;  // attention weights: 32*2048 floats

  char* ws = (char*)d_ws;
  const size_t ENC16_BYTES = 134217728ULL;  // 32*2048*1024 fp16
  _Float16* enc16 = (_Float16*)ws;
  _Float16* W16T  = (_Float16*)(ws + ENC16_BYTES);                  // 2 MB
  float* hpb      = (float*)(ws + ENC16_BYTES + 2097152);           // 128 KB
  float* logits   = (float*)(ws + ENC16_BYTES + 2097152 + 131072);  // 256 KB

  hipMemsetAsync(ctx, 0, 32 * 1024 * sizeof(float), stream);
  hipLaunchKernelGGL(prep_kernel, dim3(1152), dim3(256), 0, stream,
                     W_e, W16T, hidden, W_h, b_h, b_e, hpb);
  hipLaunchKernelGGL(attn_gemm8_kernel, dim3(256), dim3(512), 0, stream,
                     enc, enc16, W16T, hpb, v, mask, logits);
  hipLaunchKernelGGL(softmax_kernel, dim3(32), dim3(256), 0, stream, logits, wout);
  hipLaunchKernelGGL(context16_kernel, dim3(512), dim3(256), 0, stream, enc16, wout, ctx);
}

// Round 17
// 258.218 us; speedup vs baseline: 1.6393x; 1.4965x over previous
//
#include <hip/hip_runtime.h>

#define NEGV -10000000000.0f

typedef _Float16 half8 __attribute__((ext_vector_type(8)));
typedef float f32x4 __attribute__((ext_vector_type(4)));

__device__ __forceinline__ void gld16(const void* g, void* l) {
  __builtin_amdgcn_global_load_lds((const __attribute__((address_space(1))) void*)g,
                                   (__attribute__((address_space(3))) void*)l,
                                   16, 0, 0);
}

__device__ __forceinline__ float fast_tanh(float x) {
  const float e = __expf(2.0f * x);
  return 1.0f - 2.0f * __builtin_amdgcn_rcpf(e + 1.0f);
}

// ---------------------------------------------------------------------------
// PREP (one launch): blocks [0,128) hproj | [128,1152) wconv. No encconv:
// the GEMM stages A directly from fp32 (regs->cvt->ds_write), and context
// reads fp32 enc. No enc16 anywhere. (In-loop enc16 persistence was tried
// 3x -- R7/R8/R14 -- and regressed each time: vmcnt FIFO head-of-line,
// device-fence, and ledger-entanglement respectively. Closed.)
// ---------------------------------------------------------------------------
__global__ __launch_bounds__(256) void prep_kernel(
    const float* __restrict__ We, _Float16* __restrict__ W16T,
    const float* __restrict__ hidden, const float* __restrict__ W_h,
    const float* __restrict__ b_h, const float* __restrict__ b_e,
    float* __restrict__ hpb) {
  __shared__ float tile[32][33];
  const int bid = blockIdx.x;
  const int tid = threadIdx.x;

  if (bid < 128) {
    // ---- hproj ----
    const int b = bid >> 2;
    const int h = ((bid & 3) << 8) | tid;
    const float* hb = hidden + b * 1024;
    float a0 = 0.f, a1 = 0.f, a2 = 0.f, a3 = 0.f;
    #pragma unroll 4
    for (int k = 0; k < 1024; k += 4) {
      a0 = fmaf(hb[k + 0], W_h[(size_t)(k + 0) * 1024 + h], a0);
      a1 = fmaf(hb[k + 1], W_h[(size_t)(k + 1) * 1024 + h], a1);
      a2 = fmaf(hb[k + 2], W_h[(size_t)(k + 2) * 1024 + h], a2);
      a3 = fmaf(hb[k + 3], W_h[(size_t)(k + 3) * 1024 + h], a3);
    }
    hpb[b * 1024 + h] = b_h[h] + b_e[h] + ((a0 + a1) + (a2 + a3));
  } else {
    // ---- wconv: W16T[n][k] = (fp16) W_e[k][n] ----
    const int tb = bid - 128;
    const int n0 = (tb & 31) << 5, k0 = (tb >> 5) << 5;
    const int tx = tid & 31, ty = tid >> 5;  // 32 x 8
    #pragma unroll
    for (int i = 0; i < 4; ++i) {
      const int r = ty + (i << 3);
      tile[r][tx] = We[(size_t)(k0 + r) * 1024 + n0 + tx];
    }
    __syncthreads();
    #pragma unroll
    for (int i = 0; i < 4; ++i) {
      const int r = ty + (i << 3);
      W16T[(size_t)(n0 + r) * 1024 + k0 + tx] = (_Float16)tile[tx][r];
    }
  }
}

// ---------------------------------------------------------------------------
// FUSED GEMM (measured best config, 257.0us total): A staged FROM FP32
// in-loop, single barrier per K-tile, counted vmcnt (never drains):
//   logits[b,s] = mask ? v . tanh(hpb[b,:] + enc[b,s,:]@W_e) : NEG
// BM=256, BN=256 (4 panels), BK=32, 512 threads, 8 waves 2Mx4N, per-wave
// 128x64 (acc[8][4]).
//  - A: plain fp32 loads -> af regs (issued mid-t for t+2) -> cvt fp16 ->
//    dest-swizzled ds_write_b128 into 3-buffered 16KB tiles.
//  - B: gld_lds from W16T (2MB, L2-resident), pre-swizzled source, stage t+2.
//  - Ledger/tile (FIFO, in-order): start [A(t+1)x4, B(t+1)x2]; compiler's
//    af-wait at writeA retires A(t+1); issue [A(t+2)x4, B(t+2)x2];
//    tile-end vmcnt(6) retires B(t+1), leaving 6 in flight. lgkmcnt(0)
//    publishes ds_writes before the barrier.
// Swizzle: g ^= (row>>1)&3 both sides (0-conflict, verified R4-R12).
// ---------------------------------------------------------------------------
__global__ __launch_bounds__(512, 2) void attn_gemm8_kernel(
    const float* __restrict__ enc32, const _Float16* __restrict__ W16T,
    const float* __restrict__ hpb, const float* __restrict__ v,
    const int* __restrict__ mask, float* __restrict__ logits) {
  __shared__ __align__(16) _Float16 Abuf[3][256 * 32];  // 48 KB
  __shared__ __align__(16) _Float16 Bbuf[3][256 * 32];  // 48 KB
  __shared__ float hp_s[1024];
  __shared__ float vh_s[1024];
  __shared__ float red[1024];

  const int tid = threadIdx.x;
  const int wid = tid >> 6;
  const int lane = tid & 63;
  const int l15 = lane & 15;
  const int qq = lane >> 4;        // 16B granule within the 64B row
  const int wr = wid >> 2;         // 0..1: rows [wr*128, +128)
  const int wc = wid & 3;          // 0..3: cols [wc*64, +64) within the panel
  const int m0 = blockIdx.x << 8;  // 256 rows per block
  const int b = blockIdx.x >> 3;   // 8 blocks per batch

  for (int i = tid; i < 1024; i += 512) {
    hp_s[i] = hpb[(b << 10) + i];
    vh_s[i] = v[i];
  }

  // ---- staging constants ----
  const int r0 = tid >> 2;                     // A/B row, issue 0 (0..127)
  const int r1 = r0 + 128;                     // issue 1 (same swz bits)
  const int g0 = tid & 3;                      // 16B granule within 64B row
  const int swzd = (g0 ^ ((r0 >> 1) & 3)) << 4;  // dest-swizzled LDS col byte
  const int scB = swzd;                          // B source col (inverse swz)
  const int ldsoff0 = (wid << 10);
  const int ldsoff1 = (wid << 10) + 8192;

  const float* encb = enc32 + (size_t)m0 * 1024;
  const char* wb0 = (const char*)W16T;

  // A: plain fp32 loads into regs (true col = g0*8 within the 32-wide k-tile)
  f32x4 af[4];
  auto issueA = [&](int t) {
    const float* p0 = encb + (size_t)r0 * 1024 + ((t & 31) << 5) + (g0 << 3);
    const float* p1 = encb + (size_t)r1 * 1024 + ((t & 31) << 5) + (g0 << 3);
    af[0] = *(const f32x4*)p0; af[1] = *(const f32x4*)(p0 + 4);
    af[2] = *(const f32x4*)p1; af[3] = *(const f32x4*)(p1 + 4);
  };
  auto writeA = [&](int buf) {
    half8 h0, h1;
    #pragma unroll
    for (int j = 0; j < 4; ++j) {
      h0[j] = (_Float16)af[0][j]; h0[4 + j] = (_Float16)af[1][j];
      h1[j] = (_Float16)af[2][j]; h1[4 + j] = (_Float16)af[3][j];
    }
    char* Ab = (char*)(&Abuf[buf][0]);
    *(half8*)(Ab + (r0 << 6) + swzd) = h0;
    *(half8*)(Ab + (r1 << 6) + swzd) = h1;
  };
  // B: gld_lds from W16T
  auto stageB = [&](int buf, int t) {
    const char* wb = wb0 + ((size_t)(t >> 5) << 19);  // panel * 256*2048 B
    const int colb = ((t & 31) << 6) + scB;
    char* base = (char*)(&Bbuf[buf][0]);
    gld16(wb + (size_t)r0 * 2048 + colb, base + ldsoff0);
    gld16(wb + (size_t)r1 * 2048 + colb, base + ldsoff1);
  };

  // ---- read-side offsets (loop-invariant, swizzled) ----
  int aoff[2][4], boff[4];
  #pragma unroll
  for (int mh = 0; mh < 2; ++mh)
    #pragma unroll
    for (int mi = 0; mi < 4; ++mi) {
      const int row = (wr << 7) + (mh << 6) + (mi << 4) + l15;
      aoff[mh][mi] = (row << 6) + ((qq ^ ((row >> 1) & 3)) << 4);
    }
  #pragma unroll
  for (int ni = 0; ni < 4; ++ni) {
    const int np = (wc << 6) + (ni << 4) + l15;
    boff[ni] = (np << 6) + ((qq ^ ((np >> 1) & 3)) << 4);
  }

  f32x4 acc[8][4];
  float rowsum[8][4];
  #pragma unroll
  for (int mi = 0; mi < 8; ++mi)
    #pragma unroll
    for (int j = 0; j < 4; ++j) {
      acc[mi][j] = (f32x4){0.f, 0.f, 0.f, 0.f};
      rowsum[mi][j] = 0.f;
    }

  // ---- prologue: A(0)->buf0 via regs; B(0),B(1) staged; af <- A(1) ----
  issueA(0);
  stageB(0, 0); stageB(1, 1);
  asm volatile("s_waitcnt vmcnt(4)" ::: "memory");  // A(0) regs ready
  writeA(0);
  issueA(1);
  __syncthreads();  // full drain: B(0),B(1) landed, A(0) published

  #pragma unroll 1
  for (int t = 0; t < 128; ++t) {
    const int bi = t % 3;
    const int bi1 = (bi >= 2) ? 0 : bi + 1;       // (t+1)%3
    const int bi2 = (bi1 >= 2) ? 0 : bi1 + 1;     // (t+2)%3
    const char* A = (const char*)(&Abuf[bi][0]);
    const char* B = (const char*)(&Bbuf[bi][0]);
    half8 a0[4], a1[4], bf[4];

    // ---- issue all 12 ds_reads up front (compiler places counted waits) ----
    #pragma unroll
    for (int mi = 0; mi < 4; ++mi) a0[mi] = *(const half8*)(A + aoff[0][mi]);
    #pragma unroll
    for (int ni = 0; ni < 4; ++ni) bf[ni] = *(const half8*)(B + boff[ni]);
    #pragma unroll
    for (int mi = 0; mi < 4; ++mi) a1[mi] = *(const half8*)(A + aoff[1][mi]);

    // ---- cvt + write A(t+1) (af loaded during t-1; compiler waits vmcnt) ----
    if (t < 127) writeA(bi1);
    // ---- issue next loads: A(t+2) regs, B(t+2) gld_lds ----
    if (t < 126) { issueA(t + 2); stageB(bi2, t + 2); }

    // ---- MFMA clusters; reads drain underneath via per-operand waits ----
    __builtin_amdgcn_s_setprio(1);
    #pragma unroll
    for (int mi = 0; mi < 4; ++mi)
      #pragma unroll
      for (int ni = 0; ni < 4; ++ni)
        acc[mi][ni] = __builtin_amdgcn_mfma_f32_16x16x32_f16(a0[mi], bf[ni], acc[mi][ni], 0, 0, 0);
    #pragma unroll
    for (int mi = 0; mi < 4; ++mi)
      #pragma unroll
      for (int ni = 0; ni < 4; ++ni)
        acc[4 + mi][ni] = __builtin_amdgcn_mfma_f32_16x16x32_f16(a1[mi], bf[ni], acc[4 + mi][ni], 0, 0, 0);
    __builtin_amdgcn_s_setprio(0);

    // ---- tile-end sync: counted vmcnt; publish ds_writes; barrier ----
    if (t < 126) asm volatile("s_waitcnt vmcnt(6)" ::: "memory");
    else         asm volatile("s_waitcnt vmcnt(0)" ::: "memory");
    asm volatile("s_waitcnt lgkmcnt(0)" ::: "memory");
    __builtin_amdgcn_s_barrier();

    // ---- per-panel epilogue: rowsum += tanh(acc + hproj) * v ----
    if ((t & 31) == 31) {
      const int nt = t >> 5;
      const int hb = (nt << 8) + (wc << 6);
      #pragma unroll
      for (int ni = 0; ni < 4; ++ni) {
        const int h = hb + (ni << 4) + l15;
        const float hv = hp_s[h];
        const float vv = vh_s[h];
        #pragma unroll
        for (int mi = 0; mi < 8; ++mi) {
          #pragma unroll
          for (int r = 0; r < 4; ++r)
            rowsum[mi][r] += fast_tanh(acc[mi][ni][r] + hv) * vv;
          acc[mi][ni] = (f32x4){0.f, 0.f, 0.f, 0.f};
        }
      }
    }
  }

  // ---- reduce across the 16 column-lanes of each wave ----
  #pragma unroll
  for (int mi = 0; mi < 8; ++mi)
    #pragma unroll
    for (int r = 0; r < 4; ++r) {
      float s = rowsum[mi][r];
      s += __shfl_xor(s, 1);
      s += __shfl_xor(s, 2);
      s += __shfl_xor(s, 4);
      s += __shfl_xor(s, 8);
      rowsum[mi][r] = s;
    }
  __syncthreads();
  if (l15 == 0) {
    #pragma unroll
    for (int mi = 0; mi < 8; ++mi)
      #pragma unroll
      for (int r = 0; r < 4; ++r) {
        const int row = (wr << 7) + (mi << 4) + (qq << 2) + r;
        red[(row << 2) + wc] = rowsum[mi][r];
      }
  }
  __syncthreads();
  if (tid < 256) {
    const float s = red[tid << 2] + red[(tid << 2) + 1] + red[(tid << 2) + 2] + red[(tid << 2) + 3];
    const int m = m0 + tid;
    logits[m] = (mask[(b << 11) + (m & 2047)] == 0) ? NEGV : s;
  }
}

// ---------------------------------------------------------------------------
// softmax over S=2048 per batch row -> attention weights (output 1)
// ---------------------------------------------------------------------------
__global__ void softmax_kernel(const float* __restrict__ logits, float* __restrict__ wout) {
  __shared__ float red[4];
  const int b = blockIdx.x, tid = threadIdx.x;
  const int wid = tid >> 6, lane = tid & 63;
  const float* lb = logits + b * 2048;
  float x[8];
  #pragma unroll
  for (int j = 0; j < 8; ++j) x[j] = lb[tid + j * 256];
  float m = x[0];
  #pragma unroll
  for (int j = 1; j < 8; ++j) m = fmaxf(m, x[j]);
  #pragma unroll
  for (int off = 32; off > 0; off >>= 1) m = fmaxf(m, __shfl_xor(m, off));
  if (lane == 0) red[wid] = m;
  __syncthreads();
  m = fmaxf(fmaxf(red[0], red[1]), fmaxf(red[2], red[3]));
  __syncthreads();
  float e[8];
  float s = 0.f;
  #pragma unroll
  for (int j = 0; j < 8; ++j) { e[j] = expf(x[j] - m); s += e[j]; }
  #pragma unroll
  for (int off = 32; off > 0; off >>= 1) s += __shfl_xor(s, off);
  if (lane == 0) red[wid] = s;
  __syncthreads();
  s = red[0] + red[1] + red[2] + red[3];
  const float inv = 1.0f / s;
  #pragma unroll
  for (int j = 0; j < 8; ++j) wout[b * 2048 + tid + j * 256] = e[j] * inv;
}

// ---------------------------------------------------------------------------
// context from fp32 enc: ctx[b,e] = sum_s w[b,s] * enc[b,s,e]
// (at the fp32 BW floor: 256MB / 6.3 TB/s ~= 41us)
// ---------------------------------------------------------------------------
__global__ void context_kernel(const float* __restrict__ enc, const float* __restrict__ wout,
                               float* __restrict__ ctx) {
  const int b = blockIdx.x >> 4;
  const int ch = blockIdx.x & 15;
  const int tid = threadIdx.x;
  float ax = 0.f, ay = 0.f, az = 0.f, aw = 0.f;
  const int s0 = ch * 128;
  for (int i = 0; i < 128; ++i) {
    const int s = s0 + i;
    const float w = wout[b * 2048 + s];
    const float4 r = *(const float4*)(enc + (size_t)(b * 2048 + s) * 1024 + tid * 4);
    ax = fmaf(w, r.x, ax);
    ay = fmaf(w, r.y, ay);
    az = fmaf(w, r.z, az);
    aw = fmaf(w, r.w, aw);
  }
  float* c = ctx + b * 1024 + tid * 4;
  atomicAdd(c + 0, ax);
  atomicAdd(c + 1, ay);
  atomicAdd(c + 2, az);
  atomicAdd(c + 3, aw);
}

// ---------------------------------------------------------------------------
extern "C" void kernel_launch(void* const* d_in, const int* in_sizes, int n_in,
                              void* d_out, int out_size, void* d_ws, size_t ws_size,
                              hipStream_t stream) {
  const float* hidden = (const float*)d_in[0];
  const float* enc    = (const float*)d_in[1];
  const int*   mask   = (const int*)d_in[2];
  const float* W_h    = (const float*)d_in[3];
  const float* b_h    = (const float*)d_in[4];
  const float* W_e    = (const float*)d_in[5];
  const float* b_e    = (const float*)d_in[6];
  const float* v      = (const float*)d_in[7];

  float* ctx  = (float*)d_out;              // context: 32*1024 floats
  float* wout = (float*)d_out + 32 * 1024;  // attention weights: 32*2048 floats

  char* ws = (char*)d_ws;
  _Float16* W16T = (_Float16*)ws;                                   // 2 MB
  float* hpb     = (float*)(ws + 2097152);                          // 128 KB
  float* logits  = (float*)(ws + 2097152 + 131072);                 // 256 KB

  hipMemsetAsync(ctx, 0, 32 * 1024 * sizeof(float), stream);
  hipLaunchKernelGGL(prep_kernel, dim3(1152), dim3(256), 0, stream,
                     W_e, W16T, hidden, W_h, b_h, b_e, hpb);
  hipLaunchKernelGGL(attn_gemm8_kernel, dim3(256), dim3(512), 0, stream,
                     enc, W16T, hpb, v, mask, logits);
  hipLaunchKernelGGL(softmax_kernel, dim3(32), dim3(256), 0, stream, logits, wout);
  hipLaunchKernelGGL(context_kernel, dim3(512), dim3(256), 0, stream, enc, wout, ctx);
}